// Round 12
// baseline (902.194 us; speedup 1.0000x reference)
//
#include <hip/hip_runtime.h>

// ---------------------------------------------------------------------------
// 2-layer LSTM (H=51) + Linear(51,1), B=1024, T=1024, fp32.
// R25 = chunked producer-consumer layer pipeline across 128 CUs.
//   Post-mortem R24: LDS flag-barrier costs MORE than s_barrier (756us) ->
//   in-block levers truly exhausted at ~1575cy/step on 64 CUs.
//   R23 lesson: per-STEP cross-CU sync is death, but the LLC-coherent
//   machinery was CORRECT. Amortize it: sync per 32-step chunk.
//   - 128 blocks x 13 thin waves. Blocks 0..63: L1 chain for group g
//     (own LDS recurrence). Blocks 64..127: L2 chain + y for group g.
//   - h1 crosses via __device__ ring (2 chunks x 32 steps, 8MB, .bss-zero):
//     producer global_store_short sc0 sc1 (write-through to chip-wide LLC,
//     bypasses non-coherent per-XCD L2s -> NO dependence on XCD placement),
//     drained once per chunk. Consumer global_load_dwordx4 sc0 sc1,
//     double-buffered 1 step ahead, vmcnt(2) pin-waits (LLC latency hidden).
//   - Monotonic flags (__device__, 128B-padded): producer publishes
//     P0+c+1 after chunk-end vmcnt(0)+barrier; consumer gates chunk c on it
//     and publishes consumption for ring reuse. Baselines read from each
//     block's OWN flag at start -> robust across graph replays / rocprof
//     re-runs; no d_ws, no memset. Deadlock-free (producer stuck requires
//     consumer < c-1, but consumer at c' <= c-1 always has its gate open).
//   - Per-CU/step: L1 ~26 LDS reads + 13 cells; L2 ~26 reads + 13 cells +
//     4-MFMA; both ~600-750cy vs 1575 fused -> ~2x.
//   - Math bit-identical to R22: fp16 single-term MFMA, fused-rcp cells,
//     exp2-domain gates, posu/ipos layout, KPAD=88 b128. absmax 4.8828e-4.
// ---------------------------------------------------------------------------

#define H     51
#define NROW  204      // 4*H
#define TLEN  1024
#define BPB   16       // batches per block (= mfma N)
#define NTHR  832      // 13 waves
#define NG    64       // batch groups
#define NBLK  (2*NG)   // 64 producer + 64 consumer blocks
#define KPAD  88       // LDS row stride (176B)
#define CH    32       // steps per chunk
#define NCH   (TLEN/CH)
#define GW    64       // ring row width (fp16) -> 128B rows, 16B-aligned frags

#define LOG2E  1.442695041f
#define LOG2E2 2.885390082f

typedef __attribute__((ext_vector_type(8))) _Float16 half8;  // 8 f16 = 4 VGPRs
typedef __attribute__((ext_vector_type(4))) float f4;

// h1 ring + monotonic progress flags. .bss -> zeroed once at module load.
// Ring pad positions (49,51,53,55 of each... never written) stay zero forever.
__device__ __align__(16) _Float16 g_ring[NG][2 * CH][BPB][GW];   // 8 MB
__device__ int g_pflag[NG * 32];   // producer chunks published (monotonic)
__device__ int g_cflag[NG * 32];   // consumer chunks consumed  (monotonic)

__device__ __forceinline__ float frcp(float x) { return __builtin_amdgcn_rcpf(x); }
#if __has_builtin(__builtin_amdgcn_exp2f)
__device__ __forceinline__ float ex2(float x) { return __builtin_amdgcn_exp2f(x); }
#else
__device__ __forceinline__ float ex2(float x) { return __expf(x * 0.6931471806f); }
#endif

// k-layout permutation within each 8-group (R20-proven exact relabeling).
__device__ __forceinline__ int posu(int u) {
    return (u & ~7) | ((u & 3) << 1) | ((u >> 2) & 1);
}
__device__ __forceinline__ int ipos(int p) {
    return (p & ~7) | ((p & 1) << 2) | ((p >> 1) & 3);
}

__device__ __forceinline__ half8 lds8h(const _Float16* p) {  // ds_read_b128
    return *(const half8*)__builtin_assume_aligned(p, 16);
}

// ---- LLC-coherent primitives (sc0 sc1 = bypass L1+L2, hit Infinity Cache) --
__device__ __forceinline__ void ring_store16(_Float16* p, _Float16 v) {
    union { _Float16 h; unsigned short s; } u; u.h = v;
    unsigned vi = u.s;
    asm volatile("global_store_short %0, %1, off sc0 sc1"
                 :: "v"(p), "v"(vi) : "memory");
}
__device__ __forceinline__ void ring_load16B(const _Float16* p, half8* d) {
    asm volatile("global_load_dwordx4 %0, %1, off sc0 sc1"
                 : "=v"(*d) : "v"(p) : "memory");
}
__device__ __forceinline__ void wait_vm2_pin(half8* a, half8* b) {
    asm volatile("s_waitcnt vmcnt(2)" : "+v"(*a), "+v"(*b));
}
__device__ __forceinline__ void wait_vm0_pin(half8* a, half8* b) {
    asm volatile("s_waitcnt vmcnt(0)" : "+v"(*a), "+v"(*b));
}
__device__ __forceinline__ void flag_store(int* p, int v) {
    asm volatile("global_store_dword %0, %1, off sc0 sc1"
                 :: "v"(p), "v"(v) : "memory");
}
__device__ __forceinline__ int flag_load(const int* p) {
    int v;
    asm volatile("global_load_dword %0, %1, off sc0 sc1\n\ts_waitcnt vmcnt(0)"
                 : "=v"(v) : "v"(p) : "memory");
    return v;
}
__device__ __forceinline__ void wait_flag_ge(const int* p, int thr) {
    if (flag_load(p) < thr) {
        do { __builtin_amdgcn_s_sleep(2); } while (flag_load(p) < thr);
    }
    __builtin_amdgcn_sched_barrier(0);
}

#define MFMA(ACC, A, B) \
    ACC = __builtin_amdgcn_mfma_f32_16x16x32_f16((A), (B), (ACC), 0, 0, 0)

// A-frag loader (R20-proven): prow=4u+g row permutation, ipos'd k columns,
// zero-pad prow>=204 / unit>=51, log2e / 2log2e pre-scaling.
__device__ __forceinline__ half8 load_wfrag(const float* __restrict__ W,
                                            int tile, int kt, int q, int mcol)
{
    half8 hf;
    const int prow = tile * 16 + mcol;
    const float sc = ((prow & 3) == 2) ? LOG2E2 : LOG2E;
#pragma unroll
    for (int j = 0; j < 8; ++j) {
        const int kk = ipos(kt * 32 + q * 8 + j);
        float v = 0.0f;
        if (prow < NROW && kk < H) {
            const int srow = (prow & 3) * H + (prow >> 2);
            v = W[srow * H + kk];
        }
        hf[j] = (_Float16)(v * sc);
    }
    return hf;
}

// Fused LSTM cell (exp2-domain), 5 ex2 + 3 rcp. All-zero gates -> h = 0.
__device__ __forceinline__ float cell(float a_i, float a_f, float b_g,
                                      float d_o, float* c)
{
    const float e_i = ex2(-a_i);
    const float e_f = ex2(-a_f);
    const float Eg  = ex2(b_g);
    const float f   = frcp(1.0f + e_f);
    const float ig  = (Eg - 1.0f) * frcp((1.0f + e_i) * (Eg + 1.0f));
    const float cn  = fmaf(f, *c, ig);
    *c = cn;
    const float Ec  = ex2(cn * LOG2E2);
    const float e_o = ex2(-d_o);
    return (Ec - 1.0f) * frcp((Ec + 1.0f) * (1.0f + e_o));
}

__global__
__attribute__((amdgpu_flat_work_group_size(NTHR, NTHR), amdgpu_waves_per_eu(4, 4)))
void lstm2_kernel(const float* __restrict__ input,
                  const float* __restrict__ W_ih1, const float* __restrict__ W_hh1,
                  const float* __restrict__ b_ih1, const float* __restrict__ b_hh1,
                  const float* __restrict__ W_ih2, const float* __restrict__ W_hh2,
                  const float* __restrict__ b_ih2, const float* __restrict__ b_hh2,
                  const float* __restrict__ W_lin, const float* __restrict__ b_lin,
                  float* __restrict__ out)
{
    const int tid  = threadIdx.x;
    const int w    = tid >> 6;        // wave 0..12
    const int lane = tid & 63;
    const int q    = lane >> 4;
    const int mcol = lane & 15;
    const bool prod = ((int)blockIdx.x < NG);
    const int g    = (int)blockIdx.x & (NG - 1);
    const int b0   = g * BPB;

    int* pf = &g_pflag[g * 32];
    int* cf = &g_cflag[g * 32];

    // Own-layer recurrence, ping-pong (slot k&1), posu layout. Pad stays 0.
    __shared__ __align__(16) _Float16 hloc[2][BPB][KPAD];
    {
        _Float16* hz = &hloc[0][0][0];
        for (int i = tid; i < 2 * BPB * KPAD; i += NTHR) hz[i] = (_Float16)0.0f;
    }

    const int t    = w;               // tile 0..12 (thin waves)
    const int u    = 4 * t + q;       // u=51 at (w=12,q=3): dummy, h stays 0
    const int wpos = posu(u);

    if (prod) {
        // ================= L1 producer =================
        half8 A[2];
        f4 bb, wx;
#pragma unroll
        for (int kt = 0; kt < 2; ++kt) A[kt] = load_wfrag(W_hh1, t, kt, q, mcol);
#pragma unroll
        for (int j = 0; j < 4; ++j) {
            const bool v = (u < H);
            const float sc = (j == 2) ? LOG2E2 : LOG2E;
            bb[j] = v ? sc * (b_ih1[j * H + u] + b_hh1[j * H + u]) : 0.0f;
            wx[j] = v ? sc * W_ih1[j * H + u] : 0.0f;
        }
        float c1 = 0.0f;
        float xcur = input[(size_t)(b0 + mcol) * TLEN + 0];
        __syncthreads();
        const int P0 = flag_load(pf);          // own monotonic baseline

#define PSTEP(KK, JJ, WS, RS, LAST)                                            \
do {                                                                           \
    const int k_  = (KK);                                                      \
    const int kn_ = (k_ + 1 < TLEN) ? (k_ + 1) : (TLEN - 1);                   \
    const float xn_ = input[(size_t)(b0 + mcol) * TLEN + kn_];                 \
    half8 B1a = lds8h(&hloc[RS][mcol][q * 8]);                                 \
    half8 B1b = lds8h(&hloc[RS][mcol][32 + q * 8]);                            \
    f4 g1;                                                                     \
    g1[0] = fmaf(wx[0], xcur, bb[0]);                                          \
    g1[1] = fmaf(wx[1], xcur, bb[1]);                                          \
    g1[2] = fmaf(wx[2], xcur, bb[2]);                                          \
    g1[3] = fmaf(wx[3], xcur, bb[3]);                                          \
    MFMA(g1, A[0], B1a);  MFMA(g1, A[1], B1b);                                 \
    const float h = cell(g1[0], g1[1], g1[2], g1[3], &c1);                     \
    hloc[WS][mcol][wpos] = (_Float16)h;                                        \
    ring_store16(rch + ((size_t)(JJ) * BPB + mcol) * GW + wpos, (_Float16)h);  \
    if (LAST) {                                                                \
        asm volatile("s_waitcnt vmcnt(0) lgkmcnt(0)\n\ts_barrier" ::: "memory"); \
        if (tid == 0) flag_store(pf, P0 + c + 1);                              \
    } else {                                                                   \
        asm volatile("s_waitcnt lgkmcnt(0)\n\ts_barrier" ::: "memory");        \
    }                                                                          \
    xcur = xn_;                                                                \
} while (0)

        for (int c = 0; c < NCH; ++c) {
            if (c >= 2) wait_flag_ge(cf, P0 + c - 1);   // ring-slot reuse gate
            _Float16* rch = &g_ring[g][(c & 1) * CH][0][0];
            const int kb = c * CH;
            for (int jj = 0; jj < CH - 2; jj += 2) {
                PSTEP(kb + jj,     jj,     0, 1, 0);
                PSTEP(kb + jj + 1, jj + 1, 1, 0, 0);
            }
            PSTEP(kb + CH - 2, CH - 2, 0, 1, 0);
            PSTEP(kb + CH - 1, CH - 1, 1, 0, 1);        // publish chunk c
        }
#undef PSTEP
    } else {
        // ================= L2 consumer (+y) =================
        half8 Wi[2], Wh[2];
        f4 bb;
#pragma unroll
        for (int kt = 0; kt < 2; ++kt) {
            Wi[kt] = load_wfrag(W_ih2, t, kt, q, mcol);
            Wh[kt] = load_wfrag(W_hh2, t, kt, q, mcol);
        }
#pragma unroll
        for (int j = 0; j < 4; ++j) {
            const bool v = (u < H);
            const float sc = (j == 2) ? LOG2E2 : LOG2E;
            bb[j] = v ? sc * (b_ih2[j * H + u] + b_hh2[j * H + u]) : 0.0f;
        }
        float wl_a[8] = {0}, wl_b[8] = {0};   // wave 0: y weights per position
        if (w == 0) {
#pragma unroll
            for (int i = 0; i < 8; ++i) {
                const int ra = ipos(q * 8 + i);
                const int rb = ipos(32 + q * 8 + i);
                wl_a[i] = (ra < H) ? W_lin[ra] : 0.0f;
                wl_b[i] = (rb < H) ? W_lin[rb] : 0.0f;
            }
        }
        const float blin = b_lin[0];
        float c2 = 0.0f;
        __syncthreads();
        const int C0 = flag_load(cf);          // own monotonic baseline

        half8 Pa0, Pb0, Pa1, Pb1;              // h1 double buffer (static regs)

// CUR = buffer holding h1(j); NXT = buffer to prefetch h1(j+1) into.
#define CSTEP(KK, JJ, CA, CB, NA, NB, PF, LAST)                                \
do {                                                                           \
    const int j_ = (KK);                                                       \
    if (PF) {                                                                  \
        ring_load16B(rch + ((size_t)((JJ) + 1) * BPB + mcol) * GW + q * 8, &NA); \
        ring_load16B(rch + ((size_t)((JJ) + 1) * BPB + mcol) * GW + 32 + q * 8, &NB); \
        wait_vm2_pin(&CA, &CB);                                                \
    } else {                                                                   \
        wait_vm0_pin(&CA, &CB);                                                \
    }                                                                          \
    __builtin_amdgcn_sched_barrier(0);                                         \
    half8 B2a = lds8h(&hloc[((JJ) + 1) & 1][mcol][q * 8]);                     \
    half8 B2b = lds8h(&hloc[((JJ) + 1) & 1][mcol][32 + q * 8]);                \
    f4 g2 = bb;                                                                \
    MFMA(g2, Wi[0], CA);   MFMA(g2, Wi[1], CB);                                \
    MFMA(g2, Wh[0], B2a);  MFMA(g2, Wh[1], B2b);                               \
    if (w == 0 && j_ > 0) {            /* y(j-1) from B2 = h2(j-1), free */    \
        float yp = 0.0f;                                                       \
        _Pragma("unroll")                                                      \
        for (int i = 0; i < 8; ++i) {                                          \
            yp += wl_a[i] * (float)B2a[i];                                     \
            yp += wl_b[i] * (float)B2b[i];                                     \
        }                                                                      \
        yp += __shfl_xor(yp, 16);                                              \
        yp += __shfl_xor(yp, 32);                                              \
        if (q == 0) out[(size_t)(b0 + mcol) * TLEN + (j_ - 1)] = yp + blin;    \
    }                                                                          \
    const float h = cell(g2[0], g2[1], g2[2], g2[3], &c2);                     \
    hloc[(JJ) & 1][mcol][wpos] = (_Float16)h;                                  \
    if (LAST) {                                                                \
        asm volatile("s_waitcnt vmcnt(0) lgkmcnt(0)\n\ts_barrier" ::: "memory"); \
        if (tid == 0) flag_store(cf, C0 + c + 1);                              \
    } else {                                                                   \
        asm volatile("s_waitcnt lgkmcnt(0)\n\ts_barrier" ::: "memory");        \
    }                                                                          \
} while (0)

        for (int c = 0; c < NCH; ++c) {
            wait_flag_ge(pf, C0 + c + 1);      // chunk c fully written
            const _Float16* rch = &g_ring[g][(c & 1) * CH][0][0];
            const int jb = c * CH;
            ring_load16B(rch + ((size_t)0 * BPB + mcol) * GW + q * 8, &Pa0);
            ring_load16B(rch + ((size_t)0 * BPB + mcol) * GW + 32 + q * 8, &Pb0);
            for (int jj = 0; jj < CH - 2; jj += 2) {
                CSTEP(jb + jj,     jj,     Pa0, Pb0, Pa1, Pb1, 1, 0);
                CSTEP(jb + jj + 1, jj + 1, Pa1, Pb1, Pa0, Pb0, 1, 0);
            }
            CSTEP(jb + CH - 2, CH - 2, Pa0, Pb0, Pa1, Pb1, 1, 0);
            CSTEP(jb + CH - 1, CH - 1, Pa1, Pb1, Pa0, Pb0, 0, 1);  // publish
        }
#undef CSTEP

        // epilogue: y(1023) from h2(1023) = hloc slot (TLEN-1)&1 = 1
        if (w == 0) {
            half8 ya = lds8h(&hloc[1][mcol][q * 8]);
            half8 yb = lds8h(&hloc[1][mcol][32 + q * 8]);
            float yp = 0.0f;
#pragma unroll
            for (int i = 0; i < 8; ++i) {
                yp += wl_a[i] * (float)ya[i];
                yp += wl_b[i] * (float)yb[i];
            }
            yp += __shfl_xor(yp, 16);
            yp += __shfl_xor(yp, 32);
            if (q == 0) out[(size_t)(b0 + mcol) * TLEN + (TLEN - 1)] = yp + blin;
        }
    }
}

extern "C" void kernel_launch(void* const* d_in, const int* in_sizes, int n_in,
                              void* d_out, int out_size, void* d_ws, size_t ws_size,
                              hipStream_t stream)
{
    const float* input = (const float*)d_in[0];
    const float* W_ih1 = (const float*)d_in[1];
    const float* W_hh1 = (const float*)d_in[2];
    const float* b_ih1 = (const float*)d_in[3];
    const float* b_hh1 = (const float*)d_in[4];
    const float* W_ih2 = (const float*)d_in[5];
    const float* W_hh2 = (const float*)d_in[6];
    const float* b_ih2 = (const float*)d_in[7];
    const float* b_hh2 = (const float*)d_in[8];
    const float* W_lin = (const float*)d_in[9];
    const float* b_lin = (const float*)d_in[10];

    float* out = (float*)d_out;

    hipLaunchKernelGGL(lstm2_kernel, dim3(NBLK), dim3(NTHR), 0, stream,
                       input, W_ih1, W_hh1, b_ih1, b_hh1,
                       W_ih2, W_hh2, b_ih2, b_hh2, W_lin, b_lin,
                       out);
}

// Round 13
// 732.900 us; speedup vs baseline: 1.2310x; 1.2310x over previous
//
#include <hip/hip_runtime.h>

// ---------------------------------------------------------------------------
// 2-layer LSTM (H=51) + Linear(51,1), B=1024, T=1024, fp32.
// R26 = R22 (best, 672us) widened to 16 waves with SIMD-balanced roles.
//   Post-mortem R25: chunked cross-CU pipeline lost to data-path latency
//   (sc0sc1 = LLC-speed, 68GB fetch, 853us). Cross-CU handoff closed for
//   good (R23+R25). R22's residual inefficiency: 14 waves = 4/4/3/3 per
//   SIMD; barrier waits for the 4-wave SIMDs (8 cells vs 6.5 avg).
//   - 1024 thr = 16 waves = exactly 4/SIMD. Slots interleaved so round-robin
//     (w%4) gives each SIMD {L1fat, L2fat, L1light, L2light} = 7/6/6/7 cells
//     (max 8 -> 7, minimal spread):
//       w0-3:  L1 tiles {2w, 2w+1}          w4-7:  L2 tiles {2(w-4), 2(w-4)+1}
//       w8-10: L1 tile  {w}                 w12:   L2 tiles {8, 12}
//       w11:   L1 tiles {11, 12}            w13-15: L2 tile {w-4} = {9,10,11}
//   - y on w13 (lightest SIMD); its B2 frags ARE h2(k-3) -> free reads.
//   - Rest R22 verbatim: L2 lagged 2 steps, e1 shadow-read of h1(k-1) in
//     the DS-idle tail, h1 4-ring + h2 ping-pong, lgkm-only barrier, posu
//     store spread, fp16 single-term MFMA, fused-rcp exp2 cells, KPAD=88.
//   Math bit-identical to R22 -> absmax must stay 4.8828e-4.
// ---------------------------------------------------------------------------

#define H     51
#define NROW  204      // 4*H
#define TLEN  1024
#define BPB   16       // batches per block (= mfma N)
#define NTHR  1024     // 16 waves
#define NBLK  64
#define KPAD  88       // fp16 row stride (176B)
#define RING  4

#define LOG2E  1.442695041f
#define LOG2E2 2.885390082f

typedef __attribute__((ext_vector_type(8))) _Float16 half8;  // 8 f16 = 4 VGPRs
typedef __attribute__((ext_vector_type(4))) float f4;

__device__ __forceinline__ float frcp(float x) { return __builtin_amdgcn_rcpf(x); }
#if __has_builtin(__builtin_amdgcn_exp2f)
__device__ __forceinline__ float ex2(float x) { return __builtin_amdgcn_exp2f(x); }
#else
__device__ __forceinline__ float ex2(float x) { return __expf(x * 0.6931471806f); }
#endif

// k-layout permutation within each 8-group (R20-proven exact relabeling).
__device__ __forceinline__ int posu(int u) {
    return (u & ~7) | ((u & 3) << 1) | ((u >> 2) & 1);
}
__device__ __forceinline__ int ipos(int p) {
    return (p & ~7) | ((p & 1) << 2) | ((p >> 1) & 3);
}

__device__ __forceinline__ half8 lds8h(const _Float16* p) {  // ds_read_b128
    return *(const half8*)__builtin_assume_aligned(p, 16);
}

// LDS-only barrier: no vmcnt drain (xnext load stays in flight).
__device__ __forceinline__ void block_sync_lds() {
    asm volatile("s_waitcnt lgkmcnt(0)\n\ts_barrier" ::: "memory");
}

#define MFMA(ACC, A, B) \
    ACC = __builtin_amdgcn_mfma_f32_16x16x32_f16((A), (B), (ACC), 0, 0, 0)

// A-frag loader (R20-proven): prow=4u+g row permutation, ipos'd k columns,
// zero-pad prow>=204 / unit>=51, log2e / 2log2e pre-scaling.
__device__ __forceinline__ half8 load_wfrag(const float* __restrict__ W,
                                            int tile, int kt, int q, int mcol)
{
    half8 hf;
    const int prow = tile * 16 + mcol;
    const float sc = ((prow & 3) == 2) ? LOG2E2 : LOG2E;
#pragma unroll
    for (int j = 0; j < 8; ++j) {
        const int kk = ipos(kt * 32 + q * 8 + j);
        float v = 0.0f;
        if (prow < NROW && kk < H) {
            const int srow = (prow & 3) * H + (prow >> 2);
            v = W[srow * H + kk];
        }
        hf[j] = (_Float16)(v * sc);
    }
    return hf;
}

// Fused LSTM cell (exp2-domain), 5 ex2 + 3 rcp. All-zero gates -> h = 0.
__device__ __forceinline__ float cell(float a_i, float a_f, float b_g,
                                      float d_o, float* c)
{
    const float e_i = ex2(-a_i);
    const float e_f = ex2(-a_f);
    const float Eg  = ex2(b_g);
    const float f   = frcp(1.0f + e_f);
    const float ig  = (Eg - 1.0f) * frcp((1.0f + e_i) * (Eg + 1.0f));
    const float cn  = fmaf(f, *c, ig);
    *c = cn;
    const float Ec  = ex2(cn * LOG2E2);
    const float e_o = ex2(-d_o);
    return (Ec - 1.0f) * frcp((Ec + 1.0f) * (1.0f + e_o));
}

__global__
__attribute__((amdgpu_flat_work_group_size(NTHR, NTHR), amdgpu_waves_per_eu(4, 4)))
void lstm2_kernel(const float* __restrict__ input,
                  const float* __restrict__ W_ih1, const float* __restrict__ W_hh1,
                  const float* __restrict__ b_ih1, const float* __restrict__ b_hh1,
                  const float* __restrict__ W_ih2, const float* __restrict__ W_hh2,
                  const float* __restrict__ b_ih2, const float* __restrict__ b_hh2,
                  const float* __restrict__ W_lin, const float* __restrict__ b_lin,
                  float* __restrict__ out)
{
    const int tid  = threadIdx.x;
    const int w    = tid >> 6;        // wave 0..15
    const int lane = tid & 63;
    const int q    = lane >> 4;
    const int mcol = lane & 15;
    const int b0   = blockIdx.x * BPB;

    // Role + tile tables (SIMD-balanced under w%4 round-robin; see header).
    const bool isL1 = (w < 4) || (w >= 8 && w < 12);
    int t0, t1;
    bool has2;
    if (isL1) {
        const int i = (w < 4) ? w : (w - 4);      // 0..7
        if (i < 4)      { t0 = 2 * i; t1 = 2 * i + 1; has2 = true; }
        else if (i < 7) { t0 = 4 + i; t1 = 13;        has2 = false; } // 8,9,10
        else            { t0 = 11;    t1 = 12;        has2 = true;  }
    } else {
        const int i = (w < 8) ? (w - 4) : (w - 8); // 0..7
        if (i < 4)      { t0 = 2 * i; t1 = 2 * i + 1; has2 = true; }
        else if (i == 4){ t0 = 8;     t1 = 12;        has2 = true;  }
        else            { t0 = 4 + i; t1 = 13;        has2 = false; } // 9,10,11
    }
    const bool y_wave = (w == 13);

    // h1 4-ring (slot k&3) + h2 ping-pong (slot k&1); posu layout; pad = 0.
    __shared__ __align__(16) _Float16 h1r[RING][BPB][KPAD];
    __shared__ __align__(16) _Float16 h2r[2][BPB][KPAD];
    {
        _Float16* p1 = &h1r[0][0][0];
        for (int i = tid; i < RING * BPB * KPAD; i += NTHR) p1[i] = (_Float16)0.0f;
        _Float16* p2 = &h2r[0][0][0];
        for (int i = tid; i < 2 * BPB * KPAD; i += NTHR) p2[i] = (_Float16)0.0f;
    }

    // ---- persistent per-wave state ----------------------------------------
    half8 Wa[2][2], Wb[2][2];             // L1: Wa=W_hh1. L2: Wa=W_ih2, Wb=W_hh2.
    f4 bbv[2], wxv[2];
    float cc[2] = {0.0f, 0.0f};
    int wp[2];
    const int tt[2] = {t0, t1};
#pragma unroll
    for (int s = 0; s < 2; ++s) {
        const int t = tt[s];
        const int u = 4 * t + q;
        wp[s] = posu(u);
#pragma unroll
        for (int kt = 0; kt < 2; ++kt) {
            if (isL1) {
                Wa[s][kt] = load_wfrag(W_hh1, t, kt, q, mcol);
            } else {
                Wa[s][kt] = load_wfrag(W_ih2, t, kt, q, mcol);
                Wb[s][kt] = load_wfrag(W_hh2, t, kt, q, mcol);
            }
        }
#pragma unroll
        for (int j = 0; j < 4; ++j) {
            const bool v = (t < 13) && (u < H);
            const float sc = (j == 2) ? LOG2E2 : LOG2E;
            if (isL1) {
                bbv[s][j] = v ? sc * (b_ih1[j * H + u] + b_hh1[j * H + u]) : 0.0f;
                wxv[s][j] = v ? sc * W_ih1[j * H + u] : 0.0f;
            } else {
                bbv[s][j] = v ? sc * (b_ih2[j * H + u] + b_hh2[j * H + u]) : 0.0f;
                wxv[s][j] = 0.0f;
            }
        }
    }

    float wl_a[8], wl_b[8];               // w13: y weights per k-position
    if (y_wave) {
#pragma unroll
        for (int j = 0; j < 8; ++j) {
            const int ra = ipos(q * 8 + j);
            const int rb = ipos(32 + q * 8 + j);
            wl_a[j] = (ra < H) ? W_lin[ra] : 0.0f;
            wl_b[j] = (rb < H) ? W_lin[rb] : 0.0f;
        }
    }
    const float blin = b_lin[0];

    float xcur = isL1 ? input[(size_t)(b0 + mcol) * TLEN + 0] : 0.0f;
    half8 e1a = {0, 0, 0, 0, 0, 0, 0, 0};    // L2 shadow h1 frags
    half8 e1b = {0, 0, 0, 0, 0, 0, 0, 0};

    __syncthreads();                      // zeros visible (full sync once)

// Pipeline step k (R22-proven schedule). L1 computes L1(k); L2 computes
// L2(k-2) from e1=h1(k-2) (shadow-read at step k-1) + h2(k-3); y(k-3) on w13.
// ERE: shadow-read h1(k-1) from slot S1R for next step's L2.
#define STEP(KK, S1W, S1R, S2W, S2R, L1E, L2E, YE, ERE)                        \
do {                                                                           \
    const int k_ = (KK);                                                       \
    if (isL1) {                                                                \
        if (L1E) {                                                             \
            const int kn_ = (k_ + 1 < TLEN) ? (k_ + 1) : (TLEN - 1);           \
            const float xn_ = input[(size_t)(b0 + mcol) * TLEN + kn_];         \
            half8 B1a = lds8h(&h1r[S1R][mcol][q * 8]);                         \
            half8 B1b = lds8h(&h1r[S1R][mcol][32 + q * 8]);                    \
            f4 g0;                                                             \
            g0[0] = fmaf(wxv[0][0], xcur, bbv[0][0]);                          \
            g0[1] = fmaf(wxv[0][1], xcur, bbv[0][1]);                          \
            g0[2] = fmaf(wxv[0][2], xcur, bbv[0][2]);                          \
            g0[3] = fmaf(wxv[0][3], xcur, bbv[0][3]);                          \
            MFMA(g0, Wa[0][0], B1a);  MFMA(g0, Wa[0][1], B1b);                 \
            const float h0 = cell(g0[0], g0[1], g0[2], g0[3], &cc[0]);         \
            h1r[S1W][mcol][wp[0]] = (_Float16)h0;                              \
            if (has2) {                                                        \
                f4 g1;                                                         \
                g1[0] = fmaf(wxv[1][0], xcur, bbv[1][0]);                      \
                g1[1] = fmaf(wxv[1][1], xcur, bbv[1][1]);                      \
                g1[2] = fmaf(wxv[1][2], xcur, bbv[1][2]);                      \
                g1[3] = fmaf(wxv[1][3], xcur, bbv[1][3]);                      \
                MFMA(g1, Wa[1][0], B1a);  MFMA(g1, Wa[1][1], B1b);             \
                const float h1v = cell(g1[0], g1[1], g1[2], g1[3], &cc[1]);    \
                h1r[S1W][mcol][wp[1]] = (_Float16)h1v;                         \
            }                                                                  \
            xcur = xn_;                                                        \
        }                                                                      \
    } else {                                                                   \
        if (L2E) {                                                             \
            half8 B2a = lds8h(&h2r[S2R][mcol][q * 8]);                         \
            half8 B2b = lds8h(&h2r[S2R][mcol][32 + q * 8]);                    \
            f4 g0 = bbv[0];                                                    \
            MFMA(g0, Wa[0][0], e1a);  MFMA(g0, Wa[0][1], e1b);                 \
            MFMA(g0, Wb[0][0], B2a);  MFMA(g0, Wb[0][1], B2b);                 \
            f4 g1 = bbv[1];                                                    \
            if (has2) {                                                        \
                MFMA(g1, Wa[1][0], e1a);  MFMA(g1, Wa[1][1], e1b);             \
                MFMA(g1, Wb[1][0], B2a);  MFMA(g1, Wb[1][1], B2b);             \
            }                                                                  \
            if (ERE) {          /* shadow-read h1(k-1) for next step */        \
                e1a = lds8h(&h1r[S1R][mcol][q * 8]);                           \
                e1b = lds8h(&h1r[S1R][mcol][32 + q * 8]);                      \
            }                                                                  \
            if ((YE) && y_wave) {   /* y(k-3) from B2 = h2(k-3), free */       \
                float yp = 0.0f;                                               \
                _Pragma("unroll")                                              \
                for (int i = 0; i < 8; ++i) {                                  \
                    yp += wl_a[i] * (float)B2a[i];                             \
                    yp += wl_b[i] * (float)B2b[i];                             \
                }                                                              \
                yp += __shfl_xor(yp, 16);                                      \
                yp += __shfl_xor(yp, 32);                                      \
                if (q == 0) out[(size_t)(b0 + mcol) * TLEN + (k_ - 3)] = yp + blin; \
            }                                                                  \
            const float h0 = cell(g0[0], g0[1], g0[2], g0[3], &cc[0]);         \
            h2r[S2W][mcol][wp[0]] = (_Float16)h0;                              \
            if (has2) {                                                        \
                const float h1v = cell(g1[0], g1[1], g1[2], g1[3], &cc[1]);    \
                h2r[S2W][mcol][wp[1]] = (_Float16)h1v;                         \
            }                                                                  \
        } else if (ERE) {                                                      \
            e1a = lds8h(&h1r[S1R][mcol][q * 8]);                               \
            e1b = lds8h(&h1r[S1R][mcol][32 + q * 8]);                          \
        }                                                                      \
    }                                                                          \
    block_sync_lds();                                                          \
} while (0)

    // L1 at steps 0..1023; L2(k-2) at steps 2..1025; y(k-3) at 3..1025.
    STEP(0, 0, 3, 0, 1, 1, 0, 0, 0);
    STEP(1, 1, 0, 1, 0, 1, 0, 0, 1);       // shadow h1(0)
    STEP(2, 2, 1, 0, 1, 1, 1, 0, 1);       // L2(0): e1=h1(0), h2(-1)=0
    STEP(3, 3, 2, 1, 0, 1, 1, 1, 1);       // + y(0)
    for (int k = 4; k <= 1020; k += 4) {   // steady: 4..1023
        STEP(k + 0, 0, 3, 0, 1, 1, 1, 1, 1);
        STEP(k + 1, 1, 0, 1, 0, 1, 1, 1, 1);
        STEP(k + 2, 2, 1, 0, 1, 1, 1, 1, 1);
        STEP(k + 3, 3, 2, 1, 0, 1, 1, 1, 1);
    }
    STEP(1024, 0, 3, 0, 1, 0, 1, 1, 1);    // L2(1022), y(1021), shadow h1(1023)
    STEP(1025, 1, 0, 1, 0, 0, 1, 1, 0);    // L2(1023), y(1022)
#undef STEP

    // epilogue: y(1023) from h2(1023) = h2r slot 1 (written at step 1025)
    if (y_wave) {
        half8 ya = lds8h(&h2r[1][mcol][q * 8]);
        half8 yb = lds8h(&h2r[1][mcol][32 + q * 8]);
        float yp = 0.0f;
#pragma unroll
        for (int i = 0; i < 8; ++i) {
            yp += wl_a[i] * (float)ya[i];
            yp += wl_b[i] * (float)yb[i];
        }
        yp += __shfl_xor(yp, 16);
        yp += __shfl_xor(yp, 32);
        if (q == 0) out[(size_t)(b0 + mcol) * TLEN + (TLEN - 1)] = yp + blin;
    }
}

extern "C" void kernel_launch(void* const* d_in, const int* in_sizes, int n_in,
                              void* d_out, int out_size, void* d_ws, size_t ws_size,
                              hipStream_t stream)
{
    const float* input = (const float*)d_in[0];
    const float* W_ih1 = (const float*)d_in[1];
    const float* W_hh1 = (const float*)d_in[2];
    const float* b_ih1 = (const float*)d_in[3];
    const float* b_hh1 = (const float*)d_in[4];
    const float* W_ih2 = (const float*)d_in[5];
    const float* W_hh2 = (const float*)d_in[6];
    const float* b_ih2 = (const float*)d_in[7];
    const float* b_hh2 = (const float*)d_in[8];
    const float* W_lin = (const float*)d_in[9];
    const float* b_lin = (const float*)d_in[10];

    float* out = (float*)d_out;

    hipLaunchKernelGGL(lstm2_kernel, dim3(NBLK), dim3(NTHR), 0, stream,
                       input, W_ih1, W_hh1, b_ih1, b_hh1,
                       W_ih2, W_hh2, b_ih2, b_hh2, W_lin, b_lin,
                       out);
}

// Round 14
// 728.446 us; speedup vs baseline: 1.2385x; 1.0061x over previous
//
#include <hip/hip_runtime.h>

// ---------------------------------------------------------------------------
// 2-layer LSTM (H=51) + Linear(51,1), B=1024, T=1024, fp32.
// R27 = R22 restored (session best, 672us) — final kernel.
//   Session ladder: 1948 -> 1318 (2 waves/SIMD) -> 1212 (14 thin waves,
//   4/SIMD) -> 715 (fp16 single-term MFMA + exp2 fused cells) -> 672
//   (layer-split waves + lagged L2 + shadow reads). Falsified/closed:
//   VALU-issue pacing (R18/R26 null), write bank conflicts (R20 null:
//   conflicts are inherent b128-read 2-way), vmcnt drain (R20), dep depth
//   (R21), fat waves (R19: 807), software barriers (R24: 756), cross-CU
//   layer pipeline per-step (R23: 15339) and chunked-LLC (R25: 853).
//   Floor: ~1570cy/step = barrier -> 28-read DS burst (~500cy service +
//   ~220cy inherent conflicts) -> last wave's MFMA+trans tail -> barrier
//   convoy, on the 64 CUs B/BPB=16 admits. Latency/sync-structural bound;
//   no pipe >60%.
//   Structure: waves 0-6 = L1 tiles {w,7+w}; waves 7-13 = L2 (lagged 2
//   steps, h1 via shadow-read into regs during the previous step's DS-idle
//   tail); y folded into L2 wave 7 (its B2 frags ARE h2(k-3)); h1 4-ring +
//   h2 ping-pong in LDS (posu store spread, KPAD=88 conflict-free b128);
//   fp16 single-term MFMA 16x16x32; fused-rcp exp2-domain cells (5 ex2 +
//   3 rcp); bias+Wx folded into MFMA acc init; lgkm-only barrier (1/step);
//   unroll x4 with literal ring slots; peeled k=0..3 and 1024/1025.
// ---------------------------------------------------------------------------

#define H     51
#define NROW  204      // 4*H
#define TLEN  1024
#define BPB   16       // batches per block (= mfma N)
#define NTHR  896      // 14 waves
#define NBLK  64
#define KPAD  88       // fp16 row stride (176B)

#define LOG2E  1.442695041f
#define LOG2E2 2.885390082f

typedef __attribute__((ext_vector_type(8))) _Float16 half8;  // 8 f16 = 4 VGPRs
typedef __attribute__((ext_vector_type(4))) float f4;

__device__ __forceinline__ float frcp(float x) { return __builtin_amdgcn_rcpf(x); }
#if __has_builtin(__builtin_amdgcn_exp2f)
__device__ __forceinline__ float ex2(float x) { return __builtin_amdgcn_exp2f(x); }
#else
__device__ __forceinline__ float ex2(float x) { return __expf(x * 0.6931471806f); }
#endif

// k-layout permutation within each 8-group (R20-proven exact relabeling).
__device__ __forceinline__ int posu(int u) {
    return (u & ~7) | ((u & 3) << 1) | ((u >> 2) & 1);
}
__device__ __forceinline__ int ipos(int p) {   // inverse of posu
    return (p & ~7) | ((p & 1) << 2) | ((p >> 1) & 3);
}

__device__ __forceinline__ half8 lds8h(const _Float16* p) {  // ds_read_b128
    return *(const half8*)__builtin_assume_aligned(p, 16);
}

// LDS-only barrier: no vmcnt drain (xnext global load stays in flight).
__device__ __forceinline__ void block_sync_lds() {
    asm volatile("s_waitcnt lgkmcnt(0)\n\ts_barrier" ::: "memory");
}

#define MFMA(ACC, A, B) \
    ACC = __builtin_amdgcn_mfma_f32_16x16x32_f16((A), (B), (ACC), 0, 0, 0)

// A-frag loader (R20-proven): lane holds A[m=lane&15][k=quad*8+j]; source W
// [204][51] row-major, prow=4u+g permutation, column = ipos(k-position),
// zero-pad prow>=204 / unit>=51; rows pre-scaled by log2e (2log2e gate g).
__device__ __forceinline__ half8 load_wfrag(const float* __restrict__ W,
                                            int tile, int kt, int q, int mcol)
{
    half8 hf;
    const int prow = tile * 16 + mcol;
    const float sc = ((prow & 3) == 2) ? LOG2E2 : LOG2E;
#pragma unroll
    for (int j = 0; j < 8; ++j) {
        const int kk = ipos(kt * 32 + q * 8 + j);    // permuted k layout
        float v = 0.0f;
        if (prow < NROW && kk < H) {
            const int srow = (prow & 3) * H + (prow >> 2);
            v = W[srow * H + kk];
        }
        hf[j] = (_Float16)(v * sc);
    }
    return hf;
}

// Fused LSTM cell (exp2-domain pre-activations), 5 ex2 + 3 rcp (R18-proven).
// All-zero gates (dummy tiles) yield h=0 exactly (c stays 0).
__device__ __forceinline__ float cell(float a_i, float a_f, float b_g,
                                      float d_o, float* c)
{
    const float e_i = ex2(-a_i);
    const float e_f = ex2(-a_f);
    const float Eg  = ex2(b_g);
    const float f   = frcp(1.0f + e_f);
    const float ig  = (Eg - 1.0f) * frcp((1.0f + e_i) * (Eg + 1.0f));
    const float cn  = fmaf(f, *c, ig);
    *c = cn;
    const float Ec  = ex2(cn * LOG2E2);
    const float e_o = ex2(-d_o);
    return (Ec - 1.0f) * frcp((Ec + 1.0f) * (1.0f + e_o));
}

__global__
__attribute__((amdgpu_flat_work_group_size(NTHR, NTHR), amdgpu_waves_per_eu(4, 4)))
void lstm2_kernel(const float* __restrict__ input,
                  const float* __restrict__ W_ih1, const float* __restrict__ W_hh1,
                  const float* __restrict__ b_ih1, const float* __restrict__ b_hh1,
                  const float* __restrict__ W_ih2, const float* __restrict__ W_hh2,
                  const float* __restrict__ b_ih2, const float* __restrict__ b_hh2,
                  const float* __restrict__ W_lin, const float* __restrict__ b_lin,
                  float* __restrict__ out)
{
    const int tid  = threadIdx.x;
    const int w    = tid >> 6;        // wave 0..13
    const int lane = tid & 63;
    const int q    = lane >> 4;       // quad
    const int mcol = lane & 15;       // batch column (and A-frag m)
    const int b0   = blockIdx.x * BPB;

    const bool isL1 = (w < 7);
    const int  tw   = isL1 ? w : (w - 7);

    // h1 ring (4-deep, slot k&3) and h2 ping-pong (slot k&1); fp16,
    // k-permuted (posu) layout. Dummy/pad positions stay harmless.
    __shared__ __align__(16) _Float16 h1r[4][BPB][KPAD];
    __shared__ __align__(16) _Float16 h2r[2][BPB][KPAD];

    {
        _Float16* p1 = &h1r[0][0][0];
        for (int i = tid; i < 4 * BPB * KPAD; i += NTHR) p1[i] = (_Float16)0.0f;
        _Float16* p2 = &h2r[0][0][0];
        for (int i = tid; i < 2 * BPB * KPAD; i += NTHR) p2[i] = (_Float16)0.0f;
    }

    // ---- persistent per-wave state (role-dependent) ------------------------
    // L1: Wa = W_hh1 frags; bbv = bb1; wxv = wx; cc = c1.
    // L2: Wa = W_ih2, Wb = W_hh2; bbv = bb2; cc = c2.
    half8 Wa[2][2], Wb[2][2];
    f4 bbv[2], wxv[2];
    float cc[2] = {0.0f, 0.0f};
    int wp[2];
    const int tt[2] = {tw, 7 + tw};       // t=13 (w==6/13 slot1) = dummy
#pragma unroll
    for (int s = 0; s < 2; ++s) {
        const int t = tt[s];
        const int u = 4 * t + q;
        wp[s] = posu(u);
#pragma unroll
        for (int kt = 0; kt < 2; ++kt) {
            if (isL1) {
                Wa[s][kt] = load_wfrag(W_hh1, t, kt, q, mcol);
            } else {
                Wa[s][kt] = load_wfrag(W_ih2, t, kt, q, mcol);
                Wb[s][kt] = load_wfrag(W_hh2, t, kt, q, mcol);
            }
        }
#pragma unroll
        for (int j = 0; j < 4; ++j) {
            const bool v = (t < 13) && (u < H);
            const float sc = (j == 2) ? LOG2E2 : LOG2E;
            if (isL1) {
                bbv[s][j] = v ? sc * (b_ih1[j * H + u] + b_hh1[j * H + u]) : 0.0f;
                wxv[s][j] = v ? sc * W_ih1[j * H + u] : 0.0f;
            } else {
                bbv[s][j] = v ? sc * (b_ih2[j * H + u] + b_hh2[j * H + u]) : 0.0f;
                wxv[s][j] = 0.0f;
            }
        }
    }

    float wl_a[8], wl_b[8];               // wave 7: y weights per k-position
    if (w == 7) {
#pragma unroll
        for (int j = 0; j < 8; ++j) {
            const int ra = ipos(q * 8 + j);
            const int rb = ipos(32 + q * 8 + j);
            wl_a[j] = (ra < H) ? W_lin[ra] : 0.0f;
            wl_b[j] = (rb < H) ? W_lin[rb] : 0.0f;
        }
    }
    const float blin = b_lin[0];

    float xcur = isL1 ? input[(size_t)(b0 + mcol) * TLEN + 0] : 0.0f;
    half8 e1a = {0, 0, 0, 0, 0, 0, 0, 0};                 // shadow h1 frags
    half8 e1b = {0, 0, 0, 0, 0, 0, 0, 0};

    __syncthreads();                       // zeros visible (full sync once)

// One pipeline step k. L1 computes L1(k); L2 computes L2(k-2); y(k-3).
// S1W=k&3, S1R=(k+3)&3, S2W=k&1, S2R=(k+1)&1 -- passed as literals.
// ERE: shadow-read h1(k-1) (slot S1R, same data L1 reads this step) for
// next step's L2. Issued after L2 compute -> lands in the DS-idle tail.
#define STEP(KK, S1W, S1R, S2W, S2R, L1E, L2E, YE, ERE)                        \
do {                                                                           \
    const int k_ = (KK);                                                       \
    if (isL1) {                                                                \
        if (L1E) {                                                             \
            const int kn_ = (k_ + 1 < TLEN) ? (k_ + 1) : (TLEN - 1);           \
            const float xn_ = input[(size_t)(b0 + mcol) * TLEN + kn_];         \
            half8 B1a = lds8h(&h1r[S1R][mcol][q * 8]);                         \
            half8 B1b = lds8h(&h1r[S1R][mcol][32 + q * 8]);                    \
            f4 g0, g1;                                                         \
            g0[0] = fmaf(wxv[0][0], xcur, bbv[0][0]);                          \
            g0[1] = fmaf(wxv[0][1], xcur, bbv[0][1]);                          \
            g0[2] = fmaf(wxv[0][2], xcur, bbv[0][2]);                          \
            g0[3] = fmaf(wxv[0][3], xcur, bbv[0][3]);                          \
            g1[0] = fmaf(wxv[1][0], xcur, bbv[1][0]);                          \
            g1[1] = fmaf(wxv[1][1], xcur, bbv[1][1]);                          \
            g1[2] = fmaf(wxv[1][2], xcur, bbv[1][2]);                          \
            g1[3] = fmaf(wxv[1][3], xcur, bbv[1][3]);                          \
            MFMA(g0, Wa[0][0], B1a);  MFMA(g0, Wa[0][1], B1b);                 \
            MFMA(g1, Wa[1][0], B1a);  MFMA(g1, Wa[1][1], B1b);                 \
            const float h0 = cell(g0[0], g0[1], g0[2], g0[3], &cc[0]);         \
            const float h1v = cell(g1[0], g1[1], g1[2], g1[3], &cc[1]);        \
            h1r[S1W][mcol][wp[0]] = (_Float16)h0;                              \
            h1r[S1W][mcol][wp[1]] = (_Float16)h1v;                             \
            xcur = xn_;                                                        \
        }                                                                      \
    } else {                                                                   \
        if (L2E) {                                                             \
            half8 B2a = lds8h(&h2r[S2R][mcol][q * 8]);                         \
            half8 B2b = lds8h(&h2r[S2R][mcol][32 + q * 8]);                    \
            f4 g0 = bbv[0], g1 = bbv[1];                                       \
            MFMA(g0, Wa[0][0], e1a);  MFMA(g0, Wa[0][1], e1b);  /* ready */    \
            MFMA(g1, Wa[1][0], e1a);  MFMA(g1, Wa[1][1], e1b);                 \
            MFMA(g0, Wb[0][0], B2a);  MFMA(g0, Wb[0][1], B2b);                 \
            MFMA(g1, Wb[1][0], B2a);  MFMA(g1, Wb[1][1], B2b);                 \
            if (ERE) {      /* shadow-read h1(k-1) for next step's L2 */       \
                e1a = lds8h(&h1r[S1R][mcol][q * 8]);                           \
                e1b = lds8h(&h1r[S1R][mcol][32 + q * 8]);                      \
            }                                                                  \
            const float h0 = cell(g0[0], g0[1], g0[2], g0[3], &cc[0]);         \
            const float h1v = cell(g1[0], g1[1], g1[2], g1[3], &cc[1]);        \
            h2r[S2W][mcol][wp[0]] = (_Float16)h0;                              \
            h2r[S2W][mcol][wp[1]] = (_Float16)h1v;                             \
            if ((YE) && w == 7) {   /* y(k-3) from B2 = h2(k-3), free reads */ \
                float yp = 0.0f;                                               \
                _Pragma("unroll")                                              \
                for (int j = 0; j < 8; ++j) {                                  \
                    yp += wl_a[j] * (float)B2a[j];                             \
                    yp += wl_b[j] * (float)B2b[j];                             \
                }                                                              \
                yp += __shfl_xor(yp, 16);                                      \
                yp += __shfl_xor(yp, 32);                                      \
                if (q == 0) out[(size_t)(b0 + mcol) * TLEN + (k_ - 3)] = yp + blin; \
            }                                                                  \
        } else if (ERE) {                                                      \
            e1a = lds8h(&h1r[S1R][mcol][q * 8]);                               \
            e1b = lds8h(&h1r[S1R][mcol][32 + q * 8]);                          \
        }                                                                      \
    }                                                                          \
    block_sync_lds();                                                          \
} while (0)

    // Pipeline: L1 at steps 0..1023; L2(k-2) at steps 2..1025; y(k-3) at 3..1025.
    STEP(0, 0, 3, 0, 1, 1, 0, 0, 0);
    STEP(1, 1, 0, 1, 0, 1, 0, 0, 1);       // shadow-read h1(0)
    STEP(2, 2, 1, 0, 1, 1, 1, 0, 1);       // L2(0): e1=h1(0), h2(-1)=0
    STEP(3, 3, 2, 1, 0, 1, 1, 1, 1);       // + y(0)
    for (int k = 4; k <= 1020; k += 4) {   // steady: k+0..k+3 -> 4..1023
        STEP(k + 0, 0, 3, 0, 1, 1, 1, 1, 1);
        STEP(k + 1, 1, 0, 1, 0, 1, 1, 1, 1);
        STEP(k + 2, 2, 1, 0, 1, 1, 1, 1, 1);
        STEP(k + 3, 3, 2, 1, 0, 1, 1, 1, 1);
    }
    STEP(1024, 0, 3, 0, 1, 0, 1, 1, 1);    // L2(1022), y(1021), shadow h1(1023)
    STEP(1025, 1, 0, 1, 0, 0, 1, 1, 0);    // L2(1023), y(1022)
#undef STEP

    // epilogue: y(1023) from h2(1023) = h2r slot 1 (written at step 1025)
    if (w == 7) {
        half8 ya = lds8h(&h2r[1][mcol][q * 8]);
        half8 yb = lds8h(&h2r[1][mcol][32 + q * 8]);
        float yp = 0.0f;
#pragma unroll
        for (int j = 0; j < 8; ++j) {
            yp += wl_a[j] * (float)ya[j];
            yp += wl_b[j] * (float)yb[j];
        }
        yp += __shfl_xor(yp, 16);
        yp += __shfl_xor(yp, 32);
        if (q == 0) out[(size_t)(b0 + mcol) * TLEN + (TLEN - 1)] = yp + blin;
    }
}

extern "C" void kernel_launch(void* const* d_in, const int* in_sizes, int n_in,
                              void* d_out, int out_size, void* d_ws, size_t ws_size,
                              hipStream_t stream)
{
    const float* input = (const float*)d_in[0];
    const float* W_ih1 = (const float*)d_in[1];
    const float* W_hh1 = (const float*)d_in[2];
    const float* b_ih1 = (const float*)d_in[3];
    const float* b_hh1 = (const float*)d_in[4];
    const float* W_ih2 = (const float*)d_in[5];
    const float* W_hh2 = (const float*)d_in[6];
    const float* b_ih2 = (const float*)d_in[7];
    const float* b_hh2 = (const float*)d_in[8];
    const float* W_lin = (const float*)d_in[9];
    const float* b_lin = (const float*)d_in[10];

    float* out = (float*)d_out;

    hipLaunchKernelGGL(lstm2_kernel, dim3(NBLK), dim3(NTHR), 0, stream,
                       input, W_ih1, W_hh1, b_ih1, b_hh1,
                       W_ih2, W_hh2, b_ih2, b_hh2, W_lin, b_lin,
                       out);
}